// Round 8
// baseline (4073.056 us; speedup 1.0000x reference)
//
#include <hip/hip_runtime.h>
#include <math.h>

#define G 4
#define H 64
#define T 1000
#define B 32
#define ROWS (B*T)  // 32000

typedef _Float16 f16;
typedef _Float16 f16x2 __attribute__((ext_vector_type(2)));

#if defined(__has_builtin)
#if __has_builtin(__builtin_amdgcn_fdot2)
#define HAVE_FDOT2 1
#endif
#endif

__device__ __forceinline__ float dot2(f16x2 a, f16x2 b, float c) {
#ifdef HAVE_FDOT2
    return __builtin_amdgcn_fdot2(a, b, c, false);
#else
    return fmaf((float)a[0], (float)b[0], fmaf((float)a[1], (float)b[1], c));
#endif
}

__device__ __forceinline__ float sigm(float x) {
    return 1.f / (1.f + __expf(-x));
}
__device__ __forceinline__ float tanh_f(float x) {
    return 2.f / (1.f + __expf(-2.f * x)) - 1.f;
}

// ============================================================================
// Recurrence: ONE WAVE per sequence, zero barriers. Lane c owns column c and
// all 4 gate rows. Weights f16x2 in VGPRs (128), fp32 accum via v_dot2_f32_f16.
// h-broadcast: ds_write own f16 h + 8x ds_read_b128 (same-wave lgkmcnt order).
// Block = 512 thr = 8 waves = 8 seqs; launch_bounds(512,1) -> 256 VGPR budget
// (R7's (512,2) capped at 128 and spilled wpk -> 706MB scratch traffic).
// ============================================================================
template<int LAYER>
__device__ void rec_wave8(const float* __restrict__ xp,     // (128, tcmax, 256)
                          const float* __restrict__ Whh,    // (G,256,64)
                          float* __restrict__ out,          // (B,T,256)
                          float* __restrict__ stateh, float* __restrict__ statec,
                          float* __restrict__ sums,         // [512] s|ss
                          int t0, int t1, int tcmax)
{
    __builtin_amdgcn_s_setprio(1);
    __shared__ __align__(16) _Float16 hx[8][64];
    const int wv = threadIdx.x >> 6;
    const int c  = threadIdx.x & 63;
    const int sq = blockIdx.x * 8 + wv;     // g*32+b
    const int g = sq >> 5, b = sq & 31;

    // pack weights into registers: wpk[gt][k] = (W[row,2k], W[row,2k+1]) f16
    f16x2 wpk[4][32];
    #pragma unroll
    for (int gt = 0; gt < 4; ++gt) {
        const float2* wp = (const float2*)&Whh[(size_t)((g * 256 + gt * 64 + c) << 6)];
        #pragma unroll
        for (int k = 0; k < 32; ++k) {
            float2 v = wp[k];
            f16x2 r; r[0] = (f16)v.x; r[1] = (f16)v.y;
            wpk[gt][k] = r;
        }
    }

    f16x2 hpk[32];
    float cst;
    if (t0 == 0) {
        #pragma unroll
        for (int k = 0; k < 32; ++k) { f16x2 z; z[0] = (f16)0.f; z[1] = (f16)0.f; hpk[k] = z; }
        cst = 0.f;
    } else {
        const float2* sh = (const float2*)&stateh[sq * 64];
        #pragma unroll
        for (int k = 0; k < 32; ++k) {
            float2 v = sh[k];
            f16x2 r; r[0] = (f16)v.x; r[1] = (f16)v.y;
            hpk[k] = r;
        }
        cst = statec[sq * 64 + c];
    }

    const float* xpb = xp + (size_t)sq * tcmax * 256;
    float p[4][4];
    #pragma unroll
    for (int j = 0; j < 4; ++j) {
        int tp = t0 + j; if (tp > t1 - 1) tp = t1 - 1;
        #pragma unroll
        for (int gt = 0; gt < 4; ++gt)
            p[j][gt] = xpb[(size_t)(tp - t0) * 256 + gt * 64 + c];
    }

    float st_s = 0.f, st_ss = 0.f, hl = 0.f;
    const int nsteps = t1 - t0;     // multiple of 4
    for (int s4 = 0; s4 < nsteps; s4 += 4) {
        #pragma unroll
        for (int j = 0; j < 4; ++j) {
            float pre[4];
            #pragma unroll
            for (int gt = 0; gt < 4; ++gt) {
                float a0 = 0.f, a1 = 0.f;
                #pragma unroll
                for (int k = 0; k < 32; k += 2) {
                    a0 = dot2(wpk[gt][k],     hpk[k],     a0);
                    a1 = dot2(wpk[gt][k + 1], hpk[k + 1], a1);
                }
                pre[gt] = (a0 + a1) + p[j][gt];   // xp includes bias
            }
            // refill slot j (consumed 4 steps later; no barrier ever drains it)
            {
                int tp = t0 + s4 + j + 4; if (tp > t1 - 1) tp = t1 - 1;
                #pragma unroll
                for (int gt = 0; gt < 4; ++gt)
                    p[j][gt] = xpb[(size_t)(tp - t0) * 256 + gt * 64 + c];
            }
            float ig = sigm(pre[0]);
            float fg = sigm(pre[1]);
            float gg = tanh_f(pre[2]);
            float og = sigm(pre[3]);
            cst = fmaf(fg, cst, ig * gg);
            float h = og * tanh_f(cst);
            int t = t0 + s4 + j;
            if (LAYER == 1) out[((size_t)b * T + t) * 256 + c * 4 + g] = h;
            else            out[((size_t)b * T + t) * 256 + g * 64 + c] = h;
            st_s += h;
            st_ss = fmaf(h, h, st_ss);
            hl = h;
            // intra-wave h broadcast; read back as float4, reinterpret to f16x2
            hx[wv][c] = (f16)h;
            const float4* hp = (const float4*)&hx[wv][0];
            #pragma unroll
            for (int q = 0; q < 8; ++q) {
                float4 v = hp[q];
                hpk[q * 4 + 0] = __builtin_bit_cast(f16x2, v.x);
                hpk[q * 4 + 1] = __builtin_bit_cast(f16x2, v.y);
                hpk[q * 4 + 2] = __builtin_bit_cast(f16x2, v.z);
                hpk[q * 4 + 3] = __builtin_bit_cast(f16x2, v.w);
            }
        }
    }
    stateh[sq * 64 + c] = hl;
    statec[sq * 64 + c] = cst;
    int f = (LAYER == 1) ? (c * 4 + g) : (g * 64 + c);
    atomicAdd(&sums[f], st_s);
    atomicAdd(&sums[256 + f], st_ss);
}

// ============================================================================
// Projection half-tile (256 threads of a 512-thr block): 64t x 256k for one
// (g,b,tt). CONFLICT-FIX: thread's k-cols are tx+16q (stride 16), so the W
// LDS reads hit 16 CONSECUTIVE rows -> 2-way bank alias (free), instead of
// stride-4 rows -> 8-way conflict (the old 4x4 layout's hidden cost).
// ============================================================================
template<bool BN>
__device__ void proj_half(int tile, bool active,
                          const float* __restrict__ xin,
                          const float* __restrict__ Wih,
                          const float* __restrict__ bias,
                          const float* __restrict__ ac,
                          float* __restrict__ xp,
                          int t0, int tcn, int tcmax, int TT)
{
    __shared__ __align__(16) float xs[2][64][68];
    __shared__ __align__(16) float wsm[2][64][68];
    const int hf  = threadIdx.x >> 8;
    const int tid = threadIdx.x & 255;

    int id = tile;
    const int tt = id % TT; id /= TT;
    const int b = id & 31;
    const int g = id >> 5;

    const int tx = tid & 15, ty = tid >> 4;

    // stage x tile (rows t0+tt*64 .. +63), optional BN fold
    #pragma unroll
    for (int j = 0; j < 4; ++j) {
        int idx = j * 1024 + tid * 4;
        int r = idx >> 6, ci = idx & 63;
        int tg = t0 + tt * 64 + r; if (tg > T - 1) tg = T - 1;
        float4 v = *(const float4*)&xin[((size_t)b * T + tg) * 256 + g * 64 + ci];
        if (BN) {
            float4 a4 = *(const float4*)&ac[g * 64 + ci];
            float4 c4 = *(const float4*)&ac[256 + g * 64 + ci];
            v.x = fmaf(v.x, a4.x, c4.x);
            v.y = fmaf(v.y, a4.y, c4.y);
            v.z = fmaf(v.z, a4.z, c4.z);
            v.w = fmaf(v.w, a4.w, c4.w);
        }
        *(float4*)&xs[hf][r][ci] = v;
    }

    float* xpb = xp + (size_t)(g * 32 + b) * tcmax * 256;

    for (int kt = 0; kt < 4; ++kt) {
        __syncthreads();
        #pragma unroll
        for (int j = 0; j < 4; ++j) {
            int idx = j * 1024 + tid * 4;
            int r = idx >> 6, ci = idx & 63;
            float4 v = *(const float4*)&Wih[(size_t)((g * 256 + kt * 64 + r) << 6) + ci];
            *(float4*)&wsm[hf][r][ci] = v;
        }
        __syncthreads();

        float acc[4][4] = {};   // acc[a=t-sub][q=k-sub]; k-col = kt*64+tx+16q
        #pragma unroll
        for (int i4 = 0; i4 < 16; ++i4) {
            float4 xv[4], wv[4];
            #pragma unroll
            for (int q = 0; q < 4; ++q) xv[q] = *(const float4*)&xs[hf][ty * 4 + q][i4 * 4];
            #pragma unroll
            for (int q = 0; q < 4; ++q) wv[q] = *(const float4*)&wsm[hf][tx + 16 * q][i4 * 4];
            #pragma unroll
            for (int a = 0; a < 4; ++a)
                #pragma unroll
                for (int q = 0; q < 4; ++q) {
                    acc[a][q] = fmaf(xv[a].x, wv[q].x, acc[a][q]);
                    acc[a][q] = fmaf(xv[a].y, wv[q].y, acc[a][q]);
                    acc[a][q] = fmaf(xv[a].z, wv[q].z, acc[a][q]);
                    acc[a][q] = fmaf(xv[a].w, wv[q].w, acc[a][q]);
                }
        }

        float bq[4];
        #pragma unroll
        for (int q = 0; q < 4; ++q) bq[q] = bias[g * 256 + kt * 64 + tx + 16 * q];
        #pragma unroll
        for (int a = 0; a < 4; ++a) {
            int tloc = tt * 64 + ty * 4 + a;
            if (active && tloc < tcn) {
                #pragma unroll
                for (int q = 0; q < 4; ++q)
                    xpb[(size_t)tloc * 256 + kt * 64 + tx + 16 * q] = acc[a][q] + bq[q];
            }
        }
    }
}

// ============================================================================
// Fused dispatch: blocks 0..15 = 8 rec waves each (128 seqs, chunk [t0,t1));
// blocks 16.. = projection of next chunk (2 half-tiles per block).
// ============================================================================
template<int LAYER, bool PBN>
__global__ __launch_bounds__(512, 1)
void fused2(const float* __restrict__ xpA, const float* __restrict__ Whh,
            float* __restrict__ out,
            float* __restrict__ stateh, float* __restrict__ statec,
            float* __restrict__ sums,
            int t0, int t1, int tcmax,
            const float* __restrict__ xin, const float* __restrict__ Wih,
            const float* __restrict__ bias, const float* __restrict__ acbn,
            float* __restrict__ xpB, int t0n, int tcnn, int TTn, int ntiles)
{
    if (blockIdx.x < 16) {
        rec_wave8<LAYER>(xpA, Whh, out, stateh, statec, sums, t0, t1, tcmax);
    } else {
        int tile0 = (blockIdx.x - 16) * 2 + (threadIdx.x >> 8);
        bool act = tile0 < ntiles;
        int tile = act ? tile0 : (ntiles > 0 ? ntiles - 1 : 0);
        proj_half<PBN>(tile, act, xin, Wih, bias, acbn, xpB, t0n, tcnn, tcmax, TTn);
    }
}

// Standalone projection (first chunk of each layer), 512 thr / 2 half-tiles.
template<bool BN>
__global__ __launch_bounds__(512)
void xp_proj512(const float* __restrict__ xin, const float* __restrict__ Wih,
                const float* __restrict__ bias, const float* __restrict__ ac,
                float* __restrict__ xp, int t0, int tcn, int tcmax, int TT, int ntiles)
{
    int tile0 = blockIdx.x * 2 + (threadIdx.x >> 8);
    bool act = tile0 < ntiles;
    int tile = act ? tile0 : (ntiles > 0 ? ntiles - 1 : 0);
    proj_half<BN>(tile, act, xin, Wih, bias, ac, xp, t0, tcn, tcmax, TT);
}

// ============================================================================
// Fallback (proven round-1) fused rec kernel for tiny ws.
// ============================================================================
template<int LAYER>
__global__ __launch_bounds__(256, 1)
void rec_kernel(const float* __restrict__ xin,
                const float* __restrict__ Wih,
                const float* __restrict__ Whh,
                const float* __restrict__ bias,
                const float* __restrict__ bnac,
                float* __restrict__ out)
{
    const int g = blockIdx.x & 3;
    const int b = blockIdx.x >> 2;
    const int k = threadIdx.x;

    __shared__ __align__(16) float xsh[2][64];
    __shared__ __align__(16) float hsh[64];
    __shared__ __align__(16) float gsh[256];

    float wih[64], whh[64];
    {
        const float4* wi = (const float4*)(Wih + (size_t)(g * 256 + k) * 64);
        const float4* wh = (const float4*)(Whh + (size_t)(g * 256 + k) * 64);
        #pragma unroll
        for (int i = 0; i < 16; ++i) {
            float4 v = wi[i];
            wih[4*i] = v.x; wih[4*i+1] = v.y; wih[4*i+2] = v.z; wih[4*i+3] = v.w;
            float4 u = wh[i];
            whh[4*i] = u.x; whh[4*i+1] = u.y; whh[4*i+2] = u.z; whh[4*i+3] = u.w;
        }
    }
    const float bk = bias[g * 256 + k];
    const long rowbase = (long)b * T;
    const int  colbase = g * 64;

    float c = 0.f, af = 1.f, cf = 0.f;
    float xa = 0.f, xb = 0.f;

    if (k < 64) {
        if (LAYER == 2) { af = bnac[colbase + k]; cf = bnac[256 + colbase + k]; }
        hsh[k] = 0.f;
        float x0 = xin[(rowbase + 0) * 256 + colbase + k];
        xsh[0][k] = (LAYER == 2) ? fmaf(x0, af, cf) : x0;
        xa = xin[(rowbase + 1) * 256 + colbase + k];
        xb = xin[(rowbase + 2) * 256 + colbase + k];
    }
    __syncthreads();

    for (int t = 0; t < T; ++t) {
        const int cur = t & 1;
        float xn = 0.f;
        if (k < 64) {
            int tp = t + 3; if (tp > T - 1) tp = T - 1;
            xn = xin[(rowbase + tp) * 256 + colbase + k];
        }
        const float* xs = xsh[cur];
        float a0 = 0.f, a1 = 0.f, a2 = 0.f, a3 = 0.f;
        #pragma unroll
        for (int i = 0; i < 64; i += 4) {
            a0 = fmaf(wih[i],     xs[i],     a0);
            a1 = fmaf(wih[i + 1], xs[i + 1], a1);
            a2 = fmaf(wih[i + 2], xs[i + 2], a2);
            a3 = fmaf(wih[i + 3], xs[i + 3], a3);
        }
        #pragma unroll
        for (int jq = 0; jq < 64; jq += 4) {
            a0 = fmaf(whh[jq],     hsh[jq],     a0);
            a1 = fmaf(whh[jq + 1], hsh[jq + 1], a1);
            a2 = fmaf(whh[jq + 2], hsh[jq + 2], a2);
            a3 = fmaf(whh[jq + 3], hsh[jq + 3], a3);
        }
        const float acc = bk + ((a0 + a1) + (a2 + a3));
        const float act = (k >= 128 && k < 192) ? tanh_f(acc) : sigm(acc);
        gsh[k] = act;
        __syncthreads();

        if (k < 64) {
            const float ig = gsh[k];
            const float fg = gsh[64 + k];
            const float gg = gsh[128 + k];
            const float og = gsh[192 + k];
            c = fmaf(fg, c, ig * gg);
            const float h = og * tanh_f(c);
            hsh[k] = h;
            const long rrow = rowbase + t;
            if (LAYER == 1) out[rrow * 256 + k * 4 + g] = h;
            else            out[rrow * 256 + colbase + k] = h;
            xsh[cur ^ 1][k] = fmaf(xa, af, cf);
            xa = xb; xb = xn;
        }
        __syncthreads();
    }
}

// ============================================================================
// BN stats / apply
// ============================================================================
__global__ void zero_ws(float* sums, int n) {
    int i = blockIdx.x * blockDim.x + threadIdx.x;
    if (i < n) sums[i] = 0.f;
}

__global__ __launch_bounds__(256) void stats_reduce(const float* __restrict__ x,
                                                    float* __restrict__ sums)
{
    float s = 0.f, ss = 0.f;
    for (int r = blockIdx.x; r < ROWS; r += gridDim.x) {
        float v = x[(long)r * 256 + threadIdx.x];
        s += v;
        ss = fmaf(v, v, ss);
    }
    atomicAdd(&sums[threadIdx.x], s);
    atomicAdd(&sums[256 + threadIdx.x], ss);
}

__global__ void stats_finalize(const float* __restrict__ sums,
                               const float* __restrict__ gamma,
                               const float* __restrict__ beta,
                               float* __restrict__ ac)
{
    int f = threadIdx.x;
    const float invN = 1.f / (float)ROWS;
    float mean = sums[f] * invN;
    float var  = fmaf(-mean, mean, sums[256 + f] * invN);
    float a = gamma[f] * rsqrtf(var + 1e-5f);
    ac[f]       = a;
    ac[256 + f] = fmaf(-mean, a, beta[f]);
}

__global__ __launch_bounds__(256) void bn_apply(float* __restrict__ x,
                                                const float* __restrict__ ac)
{
    __shared__ float a_s[256], c_s[256];
    a_s[threadIdx.x] = ac[threadIdx.x];
    c_s[threadIdx.x] = ac[256 + threadIdx.x];
    __syncthreads();
    const long n4 = (long)ROWS * 64;
    for (long i = (long)blockIdx.x * blockDim.x + threadIdx.x; i < n4;
         i += (long)gridDim.x * blockDim.x) {
        float4 v = ((float4*)x)[i];
        int f0 = (int)((i * 4) & 255);
        v.x = fmaf(v.x, a_s[f0],     c_s[f0]);
        v.y = fmaf(v.y, a_s[f0 + 1], c_s[f0 + 1]);
        v.z = fmaf(v.z, a_s[f0 + 2], c_s[f0 + 2]);
        v.w = fmaf(v.w, a_s[f0 + 3], c_s[f0 + 3]);
        ((float4*)x)[i] = v;
    }
}

extern "C" void kernel_launch(void* const* d_in, const int* in_sizes, int n_in,
                              void* d_out, int out_size, void* d_ws, size_t ws_size,
                              hipStream_t stream)
{
    const float* inpt   = (const float*)d_in[0];
    const float* Wih1   = (const float*)d_in[1];
    const float* Whh1   = (const float*)d_in[2];
    const float* b1     = (const float*)d_in[3];
    const float* Wih2   = (const float*)d_in[4];
    const float* Whh2   = (const float*)d_in[5];
    const float* b2     = (const float*)d_in[6];
    const float* gamma1 = (const float*)d_in[7];
    const float* beta1  = (const float*)d_in[8];
    const float* gamma2 = (const float*)d_in[9];
    const float* beta2  = (const float*)d_in[10];
    float* out  = (float*)d_out;

    float* sums1 = (float*)d_ws;        // 512
    float* sums2 = sums1 + 512;         // 512
    float* acbn1 = sums2 + 512;         // 512
    float* acbn2 = acbn1 + 512;         // 512
    float* sth   = acbn2 + 512;         // 8192 (128*64)
    float* stc   = sth + 8192;          // 8192
    float* xpb   = stc + 8192;          // 2 chunk buffers

    const size_t fixedB = (size_t)(4 * 512 + 2 * 8192) * 4;  // 73728
    const long perT = 128L * 256L * 4L;                       // bytes per timestep
    long availPair = ((long)ws_size - (long)fixedB) / (2L * perT);
    int Tc = (availPair >= 500) ? 500 : (int)(availPair & ~3L);

    if (Tc >= 8) {
        float* buf[2] = { xpb, xpb + (size_t)Tc * 128 * 256 };
        const int nch = (T + Tc - 1) / Tc;
        zero_ws<<<4, 256, 0, stream>>>(sums1, 1024);   // sums1+sums2

        // ---- layer 1
        {
            int tcn0 = (Tc < T) ? Tc : T;
            int TT0 = (tcn0 + 63) / 64;
            int nt0 = 128 * TT0;
            xp_proj512<false><<<(nt0 + 1) / 2, 512, 0, stream>>>(
                inpt, Wih1, b1, nullptr, buf[0], 0, tcn0, Tc, TT0, nt0);
            for (int c = 0; c < nch; ++c) {
                int t0 = c * Tc;
                int t1 = t0 + Tc; if (t1 > T) t1 = T;
                int t0n = t1;
                int tcnn = (c + 1 < nch) ? ((T - t0n < Tc) ? (T - t0n) : Tc) : 0;
                int TTn = (tcnn + 63) / 64;
                int ntiles = 128 * TTn;
                int grid = 16 + (ntiles + 1) / 2;
                fused2<1, false><<<grid, 512, 0, stream>>>(
                    buf[c & 1], Whh1, out, sth, stc, sums1, t0, t1, Tc,
                    inpt, Wih1, b1, nullptr, buf[(c + 1) & 1], t0n, tcnn, TTn, ntiles);
            }
        }
        stats_finalize<<<1, 256, 0, stream>>>(sums1, gamma1, beta1, acbn1);

        // ---- layer 2 (BN1 fused into projection reads of `out`)
        {
            int tcn0 = (Tc < T) ? Tc : T;
            int TT0 = (tcn0 + 63) / 64;
            int nt0 = 128 * TT0;
            xp_proj512<true><<<(nt0 + 1) / 2, 512, 0, stream>>>(
                out, Wih2, b2, acbn1, buf[0], 0, tcn0, Tc, TT0, nt0);
            for (int c = 0; c < nch; ++c) {
                int t0 = c * Tc;
                int t1 = t0 + Tc; if (t1 > T) t1 = T;
                int t0n = t1;
                int tcnn = (c + 1 < nch) ? ((T - t0n < Tc) ? (T - t0n) : Tc) : 0;
                int TTn = (tcnn + 63) / 64;
                int ntiles = 128 * TTn;
                int grid = 16 + (ntiles + 1) / 2;
                // proj reads out rows [t0n,..) while rec writes rows [t0,t1): disjoint
                fused2<2, true><<<grid, 512, 0, stream>>>(
                    buf[c & 1], Whh2, out, sth, stc, sums2, t0, t1, Tc,
                    out, Wih2, b2, acbn1, buf[(c + 1) & 1], t0n, tcnn, TTn, ntiles);
            }
        }
        stats_finalize<<<1, 256, 0, stream>>>(sums2, gamma2, beta2, acbn2);
        bn_apply<<<2048, 256, 0, stream>>>(out, acbn2);
    } else {
        // ---- fallback: round-1 monolithic path (ws only needs 8 KB)
        zero_ws<<<2, 256, 0, stream>>>(sums1, 512);
        rec_kernel<1><<<G * B, 256, 0, stream>>>(inpt, Wih1, Whh1, b1, nullptr, out);
        stats_reduce<<<256, 256, 0, stream>>>(out, sums1);
        stats_finalize<<<1, 256, 0, stream>>>(sums1, gamma1, beta1, acbn1);
        rec_kernel<2><<<G * B, 256, 0, stream>>>(out, Wih2, Whh2, b2, acbn1, out);
        zero_ws<<<2, 256, 0, stream>>>(sums2, 512);
        stats_reduce<<<256, 256, 0, stream>>>(out, sums2);
        stats_finalize<<<1, 256, 0, stream>>>(sums2, gamma2, beta2, acbn2);
        bn_apply<<<2048, 256, 0, stream>>>(out, acbn2);
    }
}

// Round 9
// 1472.599 us; speedup vs baseline: 2.7659x; 2.7659x over previous
//
#include <hip/hip_runtime.h>
#include <math.h>

#define G 4
#define H 64
#define T 1000
#define B 32
#define ROWS (B*T)  // 32000

typedef _Float16 f16;
typedef _Float16 f16x2 __attribute__((ext_vector_type(2)));

#if defined(__has_builtin)
#if __has_builtin(__builtin_amdgcn_fdot2)
#define HAVE_FDOT2 1
#endif
#endif

__device__ __forceinline__ float dot2(f16x2 a, f16x2 b, float c) {
#ifdef HAVE_FDOT2
    return __builtin_amdgcn_fdot2(a, b, c, false);
#else
    return fmaf((float)a[0], (float)b[0], fmaf((float)a[1], (float)b[1], c));
#endif
}

__device__ __forceinline__ float sigm(float x) {
    return 1.f / (1.f + __expf(-x));
}
__device__ __forceinline__ float tanh_f(float x) {
    return 2.f / (1.f + __expf(-2.f * x)) - 1.f;
}

// ============================================================================
// Recurrence: ONE WAVE per sequence, zero barriers. Lane c owns column c and
// all 4 gate rows. Weights f16x2 in VGPRs (128), fp32 accum via v_dot2_f32_f16.
// h-broadcast: ds_write own f16 h + 8x ds_read_b128 (same-wave order).
// HOUSED IN 256-THREAD BLOCKS (4 waves = 4 seqs): empirically (R5 vs R7/R8),
// 256-thr + launch_bounds(256,1) gives a 244+ VGPR budget, while 512-thr
// blocks cap at 128 and spill wpk (R7/R8: 1.5-2.6 GB scratch traffic).
// ============================================================================
template<int LAYER>
__device__ void rec_wave4(const float* __restrict__ xp,     // (128, tcmax, 256)
                          const float* __restrict__ Whh,    // (G,256,64)
                          float* __restrict__ out,          // (B,T,256)
                          float* __restrict__ stateh, float* __restrict__ statec,
                          float* __restrict__ sums,         // [512] s|ss
                          int t0, int t1, int tcmax)
{
    __builtin_amdgcn_s_setprio(1);
    __shared__ __align__(16) _Float16 hx[4][64];
    const int wv = threadIdx.x >> 6;
    const int c  = threadIdx.x & 63;
    const int sq = blockIdx.x * 4 + wv;     // g*32+b
    const int g = sq >> 5, b = sq & 31;

    // pack weights into registers: wpk[gt][k] = (W[row,2k], W[row,2k+1]) f16
    f16x2 wpk[4][32];
    #pragma unroll
    for (int gt = 0; gt < 4; ++gt) {
        const float2* wp = (const float2*)&Whh[(size_t)((g * 256 + gt * 64 + c) << 6)];
        #pragma unroll
        for (int k = 0; k < 32; ++k) {
            float2 v = wp[k];
            f16x2 r; r[0] = (f16)v.x; r[1] = (f16)v.y;
            wpk[gt][k] = r;
        }
    }

    f16x2 hpk[32];
    float cst;
    if (t0 == 0) {
        #pragma unroll
        for (int k = 0; k < 32; ++k) { f16x2 z; z[0] = (f16)0.f; z[1] = (f16)0.f; hpk[k] = z; }
        cst = 0.f;
    } else {
        const float2* sh = (const float2*)&stateh[sq * 64];
        #pragma unroll
        for (int k = 0; k < 32; ++k) {
            float2 v = sh[k];
            f16x2 r; r[0] = (f16)v.x; r[1] = (f16)v.y;
            hpk[k] = r;
        }
        cst = statec[sq * 64 + c];
    }

    const float* xpb = xp + (size_t)sq * tcmax * 256;
    float p[4][4];
    #pragma unroll
    for (int j = 0; j < 4; ++j) {
        int tp = t0 + j; if (tp > t1 - 1) tp = t1 - 1;
        #pragma unroll
        for (int gt = 0; gt < 4; ++gt)
            p[j][gt] = xpb[(size_t)(tp - t0) * 256 + gt * 64 + c];
    }

    float st_s = 0.f, st_ss = 0.f, hl = 0.f;
    const int nsteps = t1 - t0;     // multiple of 4
    for (int s4 = 0; s4 < nsteps; s4 += 4) {
        #pragma unroll
        for (int j = 0; j < 4; ++j) {
            float pre[4];
            #pragma unroll
            for (int gt = 0; gt < 4; ++gt) {
                float a0 = 0.f, a1 = 0.f;
                #pragma unroll
                for (int k = 0; k < 32; k += 2) {
                    a0 = dot2(wpk[gt][k],     hpk[k],     a0);
                    a1 = dot2(wpk[gt][k + 1], hpk[k + 1], a1);
                }
                pre[gt] = (a0 + a1) + p[j][gt];   // xp includes bias
            }
            // refill slot j (consumed 4 steps later; never drained — no barriers)
            {
                int tp = t0 + s4 + j + 4; if (tp > t1 - 1) tp = t1 - 1;
                #pragma unroll
                for (int gt = 0; gt < 4; ++gt)
                    p[j][gt] = xpb[(size_t)(tp - t0) * 256 + gt * 64 + c];
            }
            float ig = sigm(pre[0]);
            float fg = sigm(pre[1]);
            float gg = tanh_f(pre[2]);
            float og = sigm(pre[3]);
            cst = fmaf(fg, cst, ig * gg);
            float h = og * tanh_f(cst);
            int t = t0 + s4 + j;
            if (LAYER == 1) out[((size_t)b * T + t) * 256 + c * 4 + g] = h;
            else            out[((size_t)b * T + t) * 256 + g * 64 + c] = h;
            st_s += h;
            st_ss = fmaf(h, h, st_ss);
            hl = h;
            // intra-wave h broadcast; read back as float4, reinterpret to f16x2
            hx[wv][c] = (f16)h;
            const float4* hp = (const float4*)&hx[wv][0];
            #pragma unroll
            for (int q = 0; q < 8; ++q) {
                float4 v = hp[q];
                hpk[q * 4 + 0] = __builtin_bit_cast(f16x2, v.x);
                hpk[q * 4 + 1] = __builtin_bit_cast(f16x2, v.y);
                hpk[q * 4 + 2] = __builtin_bit_cast(f16x2, v.z);
                hpk[q * 4 + 3] = __builtin_bit_cast(f16x2, v.w);
            }
        }
    }
    stateh[sq * 64 + c] = hl;
    statec[sq * 64 + c] = cst;
    int f = (LAYER == 1) ? (c * 4 + g) : (g * 64 + c);
    atomicAdd(&sums[f], st_s);
    atomicAdd(&sums[256 + f], st_ss);
}

// ============================================================================
// Projection tile (256 threads): 64t x 256k for one (g,b,tt); x staged once,
// kt=0..3 looped. k-cols per thread are tx+16q (stride 16) -> W LDS reads hit
// 16 consecutive rows = 2-way bank alias (free); R8 verified conflicts -> 0.
// ============================================================================
template<bool BN>
__device__ void proj_tile(int id,
                          const float* __restrict__ xin,
                          const float* __restrict__ Wih,
                          const float* __restrict__ bias,
                          const float* __restrict__ ac,
                          float* __restrict__ xp,
                          int t0, int tcn, int tcmax, int TT)
{
    __shared__ __align__(16) float xs[64][68];
    __shared__ __align__(16) float wsm[64][68];

    const int tt = id % TT; id /= TT;
    const int b = id & 31;
    const int g = id >> 5;
    const int tid = threadIdx.x;
    const int tx = tid & 15, ty = tid >> 4;

    #pragma unroll
    for (int j = 0; j < 4; ++j) {
        int idx = j * 1024 + tid * 4;
        int r = idx >> 6, ci = idx & 63;
        int tg = t0 + tt * 64 + r; if (tg > T - 1) tg = T - 1;
        float4 v = *(const float4*)&xin[((size_t)b * T + tg) * 256 + g * 64 + ci];
        if (BN) {
            float4 a4 = *(const float4*)&ac[g * 64 + ci];
            float4 c4 = *(const float4*)&ac[256 + g * 64 + ci];
            v.x = fmaf(v.x, a4.x, c4.x);
            v.y = fmaf(v.y, a4.y, c4.y);
            v.z = fmaf(v.z, a4.z, c4.z);
            v.w = fmaf(v.w, a4.w, c4.w);
        }
        *(float4*)&xs[r][ci] = v;
    }

    float* xpb = xp + (size_t)(g * 32 + b) * tcmax * 256;

    for (int kt = 0; kt < 4; ++kt) {
        __syncthreads();
        #pragma unroll
        for (int j = 0; j < 4; ++j) {
            int idx = j * 1024 + tid * 4;
            int r = idx >> 6, ci = idx & 63;
            float4 v = *(const float4*)&Wih[(size_t)((g * 256 + kt * 64 + r) << 6) + ci];
            *(float4*)&wsm[r][ci] = v;
        }
        __syncthreads();

        float acc[4][4] = {};   // acc[a=t-sub][q=k-sub]; k-col = kt*64+tx+16q
        #pragma unroll
        for (int i4 = 0; i4 < 16; ++i4) {
            float4 xv[4], wv[4];
            #pragma unroll
            for (int q = 0; q < 4; ++q) xv[q] = *(const float4*)&xs[ty * 4 + q][i4 * 4];
            #pragma unroll
            for (int q = 0; q < 4; ++q) wv[q] = *(const float4*)&wsm[tx + 16 * q][i4 * 4];
            #pragma unroll
            for (int a = 0; a < 4; ++a)
                #pragma unroll
                for (int q = 0; q < 4; ++q) {
                    acc[a][q] = fmaf(xv[a].x, wv[q].x, acc[a][q]);
                    acc[a][q] = fmaf(xv[a].y, wv[q].y, acc[a][q]);
                    acc[a][q] = fmaf(xv[a].z, wv[q].z, acc[a][q]);
                    acc[a][q] = fmaf(xv[a].w, wv[q].w, acc[a][q]);
                }
        }

        float bq[4];
        #pragma unroll
        for (int q = 0; q < 4; ++q) bq[q] = bias[g * 256 + kt * 64 + tx + 16 * q];
        #pragma unroll
        for (int a = 0; a < 4; ++a) {
            int tloc = tt * 64 + ty * 4 + a;
            if (tloc < tcn) {
                #pragma unroll
                for (int q = 0; q < 4; ++q)
                    xpb[(size_t)tloc * 256 + kt * 64 + tx + 16 * q] = acc[a][q] + bq[q];
            }
        }
    }
}

// ============================================================================
// Fused dispatch (all 256-thread blocks): 0..31 = rec (4 waves = 4 seqs each);
// 32.. = one proj tile each for the next chunk.
// ============================================================================
template<int LAYER, bool PBN>
__global__ __launch_bounds__(256, 1)
void fused3(const float* __restrict__ xpA, const float* __restrict__ Whh,
            float* __restrict__ out,
            float* __restrict__ stateh, float* __restrict__ statec,
            float* __restrict__ sums,
            int t0, int t1, int tcmax,
            const float* __restrict__ xin, const float* __restrict__ Wih,
            const float* __restrict__ bias, const float* __restrict__ acbn,
            float* __restrict__ xpB, int t0n, int tcnn, int TTn)
{
    if (blockIdx.x < 32) {
        rec_wave4<LAYER>(xpA, Whh, out, stateh, statec, sums, t0, t1, tcmax);
    } else {
        proj_tile<PBN>(blockIdx.x - 32, xin, Wih, bias, acbn, xpB,
                       t0n, tcnn, tcmax, TTn);
    }
}

// Standalone projection (first chunk of each layer).
template<bool BN>
__global__ __launch_bounds__(256)
void xp_proj(const float* __restrict__ xin, const float* __restrict__ Wih,
             const float* __restrict__ bias, const float* __restrict__ ac,
             float* __restrict__ xp, int t0, int tcn, int tcmax, int TT)
{
    proj_tile<BN>(blockIdx.x, xin, Wih, bias, ac, xp, t0, tcn, tcmax, TT);
}

// ============================================================================
// Fallback (proven round-1) fused rec kernel for tiny ws.
// ============================================================================
template<int LAYER>
__global__ __launch_bounds__(256, 1)
void rec_kernel(const float* __restrict__ xin,
                const float* __restrict__ Wih,
                const float* __restrict__ Whh,
                const float* __restrict__ bias,
                const float* __restrict__ bnac,
                float* __restrict__ out)
{
    const int g = blockIdx.x & 3;
    const int b = blockIdx.x >> 2;
    const int k = threadIdx.x;

    __shared__ __align__(16) float xsh[2][64];
    __shared__ __align__(16) float hsh[64];
    __shared__ __align__(16) float gsh[256];

    float wih[64], whh[64];
    {
        const float4* wi = (const float4*)(Wih + (size_t)(g * 256 + k) * 64);
        const float4* wh = (const float4*)(Whh + (size_t)(g * 256 + k) * 64);
        #pragma unroll
        for (int i = 0; i < 16; ++i) {
            float4 v = wi[i];
            wih[4*i] = v.x; wih[4*i+1] = v.y; wih[4*i+2] = v.z; wih[4*i+3] = v.w;
            float4 u = wh[i];
            whh[4*i] = u.x; whh[4*i+1] = u.y; whh[4*i+2] = u.z; whh[4*i+3] = u.w;
        }
    }
    const float bk = bias[g * 256 + k];
    const long rowbase = (long)b * T;
    const int  colbase = g * 64;

    float c = 0.f, af = 1.f, cf = 0.f;
    float xa = 0.f, xb = 0.f;

    if (k < 64) {
        if (LAYER == 2) { af = bnac[colbase + k]; cf = bnac[256 + colbase + k]; }
        hsh[k] = 0.f;
        float x0 = xin[(rowbase + 0) * 256 + colbase + k];
        xsh[0][k] = (LAYER == 2) ? fmaf(x0, af, cf) : x0;
        xa = xin[(rowbase + 1) * 256 + colbase + k];
        xb = xin[(rowbase + 2) * 256 + colbase + k];
    }
    __syncthreads();

    for (int t = 0; t < T; ++t) {
        const int cur = t & 1;
        float xn = 0.f;
        if (k < 64) {
            int tp = t + 3; if (tp > T - 1) tp = T - 1;
            xn = xin[(rowbase + tp) * 256 + colbase + k];
        }
        const float* xs = xsh[cur];
        float a0 = 0.f, a1 = 0.f, a2 = 0.f, a3 = 0.f;
        #pragma unroll
        for (int i = 0; i < 64; i += 4) {
            a0 = fmaf(wih[i],     xs[i],     a0);
            a1 = fmaf(wih[i + 1], xs[i + 1], a1);
            a2 = fmaf(wih[i + 2], xs[i + 2], a2);
            a3 = fmaf(wih[i + 3], xs[i + 3], a3);
        }
        #pragma unroll
        for (int jq = 0; jq < 64; jq += 4) {
            a0 = fmaf(whh[jq],     hsh[jq],     a0);
            a1 = fmaf(whh[jq + 1], hsh[jq + 1], a1);
            a2 = fmaf(whh[jq + 2], hsh[jq + 2], a2);
            a3 = fmaf(whh[jq + 3], hsh[jq + 3], a3);
        }
        const float acc = bk + ((a0 + a1) + (a2 + a3));
        const float act = (k >= 128 && k < 192) ? tanh_f(acc) : sigm(acc);
        gsh[k] = act;
        __syncthreads();

        if (k < 64) {
            const float ig = gsh[k];
            const float fg = gsh[64 + k];
            const float gg = gsh[128 + k];
            const float og = gsh[192 + k];
            c = fmaf(fg, c, ig * gg);
            const float h = og * tanh_f(c);
            hsh[k] = h;
            const long rrow = rowbase + t;
            if (LAYER == 1) out[rrow * 256 + k * 4 + g] = h;
            else            out[rrow * 256 + colbase + k] = h;
            xsh[cur ^ 1][k] = fmaf(xa, af, cf);
            xa = xb; xb = xn;
        }
        __syncthreads();
    }
}

// ============================================================================
// BN stats / apply
// ============================================================================
__global__ void zero_ws(float* sums, int n) {
    int i = blockIdx.x * blockDim.x + threadIdx.x;
    if (i < n) sums[i] = 0.f;
}

__global__ __launch_bounds__(256) void stats_reduce(const float* __restrict__ x,
                                                    float* __restrict__ sums)
{
    float s = 0.f, ss = 0.f;
    for (int r = blockIdx.x; r < ROWS; r += gridDim.x) {
        float v = x[(long)r * 256 + threadIdx.x];
        s += v;
        ss = fmaf(v, v, ss);
    }
    atomicAdd(&sums[threadIdx.x], s);
    atomicAdd(&sums[256 + threadIdx.x], ss);
}

__global__ void stats_finalize(const float* __restrict__ sums,
                               const float* __restrict__ gamma,
                               const float* __restrict__ beta,
                               float* __restrict__ ac)
{
    int f = threadIdx.x;
    const float invN = 1.f / (float)ROWS;
    float mean = sums[f] * invN;
    float var  = fmaf(-mean, mean, sums[256 + f] * invN);
    float a = gamma[f] * rsqrtf(var + 1e-5f);
    ac[f]       = a;
    ac[256 + f] = fmaf(-mean, a, beta[f]);
}

__global__ __launch_bounds__(256) void bn_apply(float* __restrict__ x,
                                                const float* __restrict__ ac)
{
    __shared__ float a_s[256], c_s[256];
    a_s[threadIdx.x] = ac[threadIdx.x];
    c_s[threadIdx.x] = ac[256 + threadIdx.x];
    __syncthreads();
    const long n4 = (long)ROWS * 64;
    for (long i = (long)blockIdx.x * blockDim.x + threadIdx.x; i < n4;
         i += (long)gridDim.x * blockDim.x) {
        float4 v = ((float4*)x)[i];
        int f0 = (int)((i * 4) & 255);
        v.x = fmaf(v.x, a_s[f0],     c_s[f0]);
        v.y = fmaf(v.y, a_s[f0 + 1], c_s[f0 + 1]);
        v.z = fmaf(v.z, a_s[f0 + 2], c_s[f0 + 2]);
        v.w = fmaf(v.w, a_s[f0 + 3], c_s[f0 + 3]);
        ((float4*)x)[i] = v;
    }
}

extern "C" void kernel_launch(void* const* d_in, const int* in_sizes, int n_in,
                              void* d_out, int out_size, void* d_ws, size_t ws_size,
                              hipStream_t stream)
{
    const float* inpt   = (const float*)d_in[0];
    const float* Wih1   = (const float*)d_in[1];
    const float* Whh1   = (const float*)d_in[2];
    const float* b1     = (const float*)d_in[3];
    const float* Wih2   = (const float*)d_in[4];
    const float* Whh2   = (const float*)d_in[5];
    const float* b2     = (const float*)d_in[6];
    const float* gamma1 = (const float*)d_in[7];
    const float* beta1  = (const float*)d_in[8];
    const float* gamma2 = (const float*)d_in[9];
    const float* beta2  = (const float*)d_in[10];
    float* out  = (float*)d_out;

    float* sums1 = (float*)d_ws;        // 512
    float* sums2 = sums1 + 512;         // 512
    float* acbn1 = sums2 + 512;         // 512
    float* acbn2 = acbn1 + 512;         // 512
    float* sth   = acbn2 + 512;         // 8192 (128*64)
    float* stc   = sth + 8192;          // 8192
    float* xpb   = stc + 8192;          // 2 chunk buffers

    const size_t fixedB = (size_t)(4 * 512 + 2 * 8192) * 4;  // 73728
    const long perT = 128L * 256L * 4L;                       // bytes per timestep
    long availPair = ((long)ws_size - (long)fixedB) / (2L * perT);
    int Tc = (availPair >= 500) ? 500 : (int)(availPair & ~3L);

    if (Tc >= 8) {
        float* buf[2] = { xpb, xpb + (size_t)Tc * 128 * 256 };
        const int nch = (T + Tc - 1) / Tc;
        zero_ws<<<4, 256, 0, stream>>>(sums1, 1024);   // sums1+sums2

        // ---- layer 1
        {
            int tcn0 = (Tc < T) ? Tc : T;
            int TT0 = (tcn0 + 63) / 64;
            xp_proj<false><<<128 * TT0, 256, 0, stream>>>(
                inpt, Wih1, b1, nullptr, buf[0], 0, tcn0, Tc, TT0);
            for (int c = 0; c < nch; ++c) {
                int t0 = c * Tc;
                int t1 = t0 + Tc; if (t1 > T) t1 = T;
                int t0n = t1;
                int tcnn = (c + 1 < nch) ? ((T - t0n < Tc) ? (T - t0n) : Tc) : 0;
                int TTn = (tcnn + 63) / 64;
                int grid = 32 + 128 * TTn;
                fused3<1, false><<<grid, 256, 0, stream>>>(
                    buf[c & 1], Whh1, out, sth, stc, sums1, t0, t1, Tc,
                    inpt, Wih1, b1, nullptr, buf[(c + 1) & 1], t0n, tcnn, TTn);
            }
        }
        stats_finalize<<<1, 256, 0, stream>>>(sums1, gamma1, beta1, acbn1);

        // ---- layer 2 (BN1 fused into projection reads of `out`)
        {
            int tcn0 = (Tc < T) ? Tc : T;
            int TT0 = (tcn0 + 63) / 64;
            xp_proj<true><<<128 * TT0, 256, 0, stream>>>(
                out, Wih2, b2, acbn1, buf[0], 0, tcn0, Tc, TT0);
            for (int c = 0; c < nch; ++c) {
                int t0 = c * Tc;
                int t1 = t0 + Tc; if (t1 > T) t1 = T;
                int t0n = t1;
                int tcnn = (c + 1 < nch) ? ((T - t0n < Tc) ? (T - t0n) : Tc) : 0;
                int TTn = (tcnn + 63) / 64;
                int grid = 32 + 128 * TTn;
                // proj reads out rows [t0n,..) while rec writes rows [t0,t1): disjoint
                fused3<2, true><<<grid, 256, 0, stream>>>(
                    buf[c & 1], Whh2, out, sth, stc, sums2, t0, t1, Tc,
                    out, Wih2, b2, acbn1, buf[(c + 1) & 1], t0n, tcnn, TTn);
            }
        }
        stats_finalize<<<1, 256, 0, stream>>>(sums2, gamma2, beta2, acbn2);
        bn_apply<<<2048, 256, 0, stream>>>(out, acbn2);
    } else {
        // ---- fallback: round-1 monolithic path (ws only needs 8 KB)
        zero_ws<<<2, 256, 0, stream>>>(sums1, 512);
        rec_kernel<1><<<G * B, 256, 0, stream>>>(inpt, Wih1, Whh1, b1, nullptr, out);
        stats_reduce<<<256, 256, 0, stream>>>(out, sums1);
        stats_finalize<<<1, 256, 0, stream>>>(sums1, gamma1, beta1, acbn1);
        rec_kernel<2><<<G * B, 256, 0, stream>>>(out, Wih2, Whh2, b2, acbn1, out);
        zero_ws<<<2, 256, 0, stream>>>(sums2, 512);
        stats_reduce<<<256, 256, 0, stream>>>(out, sums2);
        stats_finalize<<<1, 256, 0, stream>>>(sums2, gamma2, beta2, acbn2);
        bn_apply<<<2048, 256, 0, stream>>>(out, acbn2);
    }
}